// Round 1
// baseline (1916.844 us; speedup 1.0000x reference)
//
#include <hip/hip_runtime.h>
#include <hip/hip_bf16.h>

#define DD 64
#define EPSV 1e-5f

static __device__ __forceinline__ float fatomic_add(float* p, float v) {
#if defined(__HIP_DEVICE_COMPILE__)
    return unsafeAtomicAdd(p, v);
#else
    return 0.f;
#endif
}

static __device__ __forceinline__ float gelu_exact(float x) {
    return 0.5f * x * (1.0f + erff(x * 0.70710678118654752f));
}

// ---------------- degree ----------------
__global__ void k_init_deg(float* deg, int n) {
    int i = blockIdx.x * 256 + threadIdx.x;
    if (i < n) deg[i] = 1.0f;  // self-loop
}

__global__ void k_deg_accum(const int* __restrict__ dst, float* deg, int e) {
    int i = blockIdx.x * 256 + threadIdx.x;
    if (i < e) fatomic_add(&deg[dst[i]], 1.0f);
}

__global__ void k_dinv(float* deg, int n) {
    int i = blockIdx.x * 256 + threadIdx.x;
    if (i < n) deg[i] = rsqrtf(deg[i]);  // deg >= 1 always
}

// ---------------- GEMM [n,64] @ [64,64] ----------------
__global__ __launch_bounds__(256) void k_gemm64(const float* __restrict__ h,
                                                const float* __restrict__ W,
                                                float* __restrict__ out, int n) {
    __shared__ float Wl[64 * 64];
    int t = threadIdx.x;
    for (int i = t; i < 64 * 64; i += 256) Wl[i] = W[i];
    __syncthreads();
    int lane = t & 63, wv = t >> 6;
    for (int r = blockIdx.x * 4 + wv; r < n; r += gridDim.x * 4) {
        float hv = h[r * 64 + lane];
        float acc = 0.f;
#pragma unroll
        for (int k = 0; k < 64; ++k) {
            float a = __shfl(hv, k, 64);
            acc += a * Wl[k * 64 + lane];
        }
        out[r * 64 + lane] = acc;
    }
}

// ---------------- aggregation ----------------
__global__ void k_agg_init(const float* __restrict__ hw, const float* __restrict__ dinv,
                           const float* __restrict__ convB, float* __restrict__ agg, int n) {
    int t = blockIdx.x * 256 + threadIdx.x;
    if (t >= n * 64) return;
    int node = t >> 6, c = t & 63;
    float di = dinv[node];
    agg[t] = di * di * hw[t] + convB[c];  // self-loop term + bias
}

__global__ __launch_bounds__(256) void k_edge_scatter(const int* __restrict__ src,
                                                      const int* __restrict__ dst,
                                                      const float* __restrict__ dinv,
                                                      const float* __restrict__ hw,
                                                      float* __restrict__ agg, int e) {
    int idx = blockIdx.x * 4 + (threadIdx.x >> 6);
    int lane = threadIdx.x & 63;
    if (idx >= e) return;
    int s = src[idx], d = dst[idx];
    float w = dinv[s] * dinv[d];
    fatomic_add(&agg[d * 64 + lane], w * hw[s * 64 + lane]);
}

// ---------------- batchnorm stats ----------------
__global__ __launch_bounds__(256) void k_bn_stats(const float* __restrict__ agg,
                                                  float* gsum, float* gsumsq, int n) {
    int t = threadIdx.x;
    int lane = t & 63, wv = t >> 6;
    float s = 0.f, sq = 0.f;
    for (int r = blockIdx.x * 4 + wv; r < n; r += gridDim.x * 4) {
        float v = agg[r * 64 + lane];
        s += v;
        sq += v * v;
    }
    __shared__ float ls[256], lq[256];
    ls[t] = s;
    lq[t] = sq;
    __syncthreads();
    if (t < 64) {
        float fs = ls[t] + ls[t + 64] + ls[t + 128] + ls[t + 192];
        float fq = lq[t] + lq[t + 64] + lq[t + 128] + lq[t + 192];
        fatomic_add(&gsum[t], fs);
        fatomic_add(&gsumsq[t], fq);
    }
}

// ---------------- BN + residual + LN + GELU ----------------
__global__ __launch_bounds__(256) void k_bn_ln_gelu(const float* __restrict__ agg,
                                                    const float* __restrict__ xin,
                                                    const float* __restrict__ gsum,
                                                    const float* __restrict__ gsumsq,
                                                    const float* __restrict__ bng,
                                                    const float* __restrict__ bnb,
                                                    const float* __restrict__ lng,
                                                    const float* __restrict__ lnb,
                                                    float* __restrict__ out, int n, int has_res) {
    int t = threadIdx.x;
    int lane = t & 63, wv = t >> 6;
    float invN = 1.0f / (float)n;
    float mu_c = gsum[lane] * invN;
    float var_c = gsumsq[lane] * invN - mu_c * mu_c;
    float bscale = rsqrtf(var_c + EPSV) * bng[lane];
    float bshift = bnb[lane];
    float lg = lng[lane], lb = lnb[lane];
    for (int r = blockIdx.x * 4 + wv; r < n; r += gridDim.x * 4) {
        float x = agg[r * 64 + lane];
        float hb = (x - mu_c) * bscale + bshift;
        if (has_res) hb += xin[r * 64 + lane];
        float ssum = hb;
#pragma unroll
        for (int off = 32; off; off >>= 1) ssum += __shfl_xor(ssum, off, 64);
        float rmu = ssum * (1.f / 64.f);
        float d = hb - rmu;
        float vs = d * d;
#pragma unroll
        for (int off = 32; off; off >>= 1) vs += __shfl_xor(vs, off, 64);
        float rvar = vs * (1.f / 64.f);
        float ln = d * rsqrtf(rvar + EPSV) * lg + lb;
        out[r * 64 + lane] = gelu_exact(ln);
    }
}

// ---------------- pooling ----------------
__global__ void k_pool_accum(const float* __restrict__ h, const int* __restrict__ batch,
                             float* psum, unsigned* pmax, float* cnt, int n) {
    int t = blockIdx.x * 256 + threadIdx.x;
    int node = t >> 6, lane = t & 63;
    if (node >= n) return;
    int g = batch[node];
    float v = h[node * 64 + lane];
    fatomic_add(&psum[g * 64 + lane], v);
    unsigned u = __float_as_uint(v);
    u = (u & 0x80000000u) ? ~u : (u | 0x80000000u);
    atomicMax(&pmax[g * 64 + lane], u);
    if (lane == 0) fatomic_add(&cnt[g], 1.0f);
}

__global__ void k_build_z(const float* __restrict__ psum, const unsigned* __restrict__ pmax,
                          const float* __restrict__ cnt, float* __restrict__ z, int g_total) {
    int t = blockIdx.x * 256 + threadIdx.x;
    if (t >= g_total * 64) return;
    int g = t >> 6, c = t & 63;
    float s = psum[t];
    float nc = cnt[g];
    float mean = s / fmaxf(nc, 1.0f);
    float mx = 0.f;
    if (nc > 0.f) {
        unsigned u = pmax[t];
        u = (u & 0x80000000u) ? (u ^ 0x80000000u) : ~u;
        mx = __uint_as_float(u);
    }
    z[g * 192 + c] = mean;
    z[g * 192 + 64 + c] = mx;
    z[g * 192 + 128 + c] = s;
}

// ---------------- MLP head (one block per graph) ----------------
__global__ __launch_bounds__(128) void k_head(const float* __restrict__ z,
                                              const float* __restrict__ W1, const float* __restrict__ b1,
                                              const float* __restrict__ ln1g, const float* __restrict__ ln1b,
                                              const float* __restrict__ W2, const float* __restrict__ b2,
                                              const float* __restrict__ ln2g, const float* __restrict__ ln2b,
                                              const float* __restrict__ W3, const float* __restrict__ b3,
                                              float* __restrict__ out) {
    int g = blockIdx.x;
    int t = threadIdx.x;
    int lane = t & 63, wv = t >> 6;
    __shared__ float zl[192], h1[128], red[2];
    for (int i = t; i < 192; i += 128) zl[i] = z[g * 192 + i];
    __syncthreads();
    // layer 1: [192] @ [192,128]
    float acc = b1[t];
    for (int k = 0; k < 192; ++k) acc += zl[k] * W1[k * 128 + t];
    // LN over 128 (two waves)
    float s = acc;
#pragma unroll
    for (int off = 32; off; off >>= 1) s += __shfl_xor(s, off, 64);
    if (lane == 0) red[wv] = s;
    __syncthreads();
    float mu = (red[0] + red[1]) * (1.f / 128.f);
    float d = acc - mu;
    float q = d * d;
#pragma unroll
    for (int off = 32; off; off >>= 1) q += __shfl_xor(q, off, 64);
    __syncthreads();
    if (lane == 0) red[wv] = q;
    __syncthreads();
    float var = (red[0] + red[1]) * (1.f / 128.f);
    float ln = d * rsqrtf(var + EPSV) * ln1g[t] + ln1b[t];
    h1[t] = gelu_exact(ln);
    __syncthreads();
    // layer 2: [128] @ [128,64] — wave 0 only
    if (t < 64) {
        float acc2 = b2[t];
        for (int k = 0; k < 128; ++k) acc2 += h1[k] * W2[k * 64 + t];
        float s2 = acc2;
#pragma unroll
        for (int off = 32; off; off >>= 1) s2 += __shfl_xor(s2, off, 64);
        float mu2 = s2 * (1.f / 64.f);
        float d2 = acc2 - mu2;
        float q2 = d2 * d2;
#pragma unroll
        for (int off = 32; off; off >>= 1) q2 += __shfl_xor(q2, off, 64);
        float var2 = q2 * (1.f / 64.f);
        float l2 = d2 * rsqrtf(var2 + EPSV) * ln2g[t] + ln2b[t];
        float g2 = gelu_exact(l2);
        float p = g2 * W3[t];
#pragma unroll
        for (int off = 32; off; off >>= 1) p += __shfl_xor(p, off, 64);
        if (t == 0) out[g] = p + b3[0];
    }
}

extern "C" void kernel_launch(void* const* d_in, const int* in_sizes, int n_in,
                              void* d_out, int out_size, void* d_ws, size_t ws_size,
                              hipStream_t stream) {
    const float* x      = (const float*)d_in[0];
    const int*   eidx   = (const int*)d_in[1];
    const int*   batch  = (const int*)d_in[2];
    const float* convW  = (const float*)d_in[3];
    const float* convB  = (const float*)d_in[4];
    const float* bn_g   = (const float*)d_in[5];
    const float* bn_b   = (const float*)d_in[6];
    const float* ln_g   = (const float*)d_in[7];
    const float* ln_b   = (const float*)d_in[8];
    const float* W1     = (const float*)d_in[9];
    const float* b1     = (const float*)d_in[10];
    const float* ln1g   = (const float*)d_in[11];
    const float* ln1b   = (const float*)d_in[12];
    const float* W2     = (const float*)d_in[13];
    const float* b2     = (const float*)d_in[14];
    const float* ln2g   = (const float*)d_in[15];
    const float* ln2b   = (const float*)d_in[16];
    const float* W3     = (const float*)d_in[17];
    const float* b3     = (const float*)d_in[18];
    float* out = (float*)d_out;

    const int N = in_sizes[0] / DD;
    const int E = in_sizes[1] / 2;
    const int G = out_size;  // [G,1]
    const int* esrc = eidx;
    const int* edst = eidx + E;

    // workspace layout
    char* ws = (char*)d_ws;
    size_t off = 0;
    auto alloc = [&](size_t bytes) {
        size_t p = off;
        off = (off + bytes + 255) & ~(size_t)255;
        return (void*)(ws + p);
    };
    float* dinv   = (float*)alloc((size_t)N * 4);
    float* bufA   = (float*)alloc((size_t)N * DD * 4);
    float* bufB   = (float*)alloc((size_t)N * DD * 4);
    float* bufC   = (float*)alloc((size_t)N * DD * 4);
    float* gstats = (float*)alloc(2 * DD * 4);  // gsum | gsumsq
    float* gsum   = gstats;
    float* gsumsq = gstats + DD;
    char*  poolraw = (char*)alloc((size_t)G * DD * 4 * 2 + (size_t)G * 4);
    float*    psum = (float*)poolraw;
    unsigned* pmax = (unsigned*)(poolraw + (size_t)G * DD * 4);
    float*    cnt  = (float*)(poolraw + (size_t)G * DD * 4 * 2);
    float* z = (float*)alloc((size_t)G * 3 * DD * 4);
    (void)ws_size; (void)n_in;

    // degree / dinv
    k_init_deg<<<(N + 255) / 256, 256, 0, stream>>>(dinv, N);
    k_deg_accum<<<(E + 255) / 256, 256, 0, stream>>>(edst, dinv, E);
    k_dinv<<<(N + 255) / 256, 256, 0, stream>>>(dinv, N);

    // layer buffer rotation: {h_in, hw, agg, h_out}
    const float* hin[3] = {x, bufC, bufA};
    float* hw[3]  = {bufA, bufA, bufB};
    float* agg[3] = {bufB, bufB, bufC};
    float* hout[3] = {bufC, bufA, bufB};

    int ew_blocks = (E + 3) / 4;
    int nd_blocks = (N * DD + 255) / 256;

    for (int l = 0; l < 3; ++l) {
        k_gemm64<<<1024, 256, 0, stream>>>(hin[l], convW + (size_t)l * DD * DD, hw[l], N);
        k_agg_init<<<nd_blocks, 256, 0, stream>>>(hw[l], dinv, convB + l * DD, agg[l], N);
        k_edge_scatter<<<ew_blocks, 256, 0, stream>>>(esrc, edst, dinv, hw[l], agg[l], E);
        hipMemsetAsync(gstats, 0, 2 * DD * 4, stream);
        k_bn_stats<<<512, 256, 0, stream>>>(agg[l], gsum, gsumsq, N);
        k_bn_ln_gelu<<<1024, 256, 0, stream>>>(agg[l], hin[l], gsum, gsumsq,
                                               bn_g + l * DD, bn_b + l * DD,
                                               ln_g + l * DD, ln_b + l * DD,
                                               hout[l], N, l > 0 ? 1 : 0);
    }

    // pooling
    hipMemsetAsync(poolraw, 0, (size_t)G * DD * 4 * 2 + (size_t)G * 4, stream);
    k_pool_accum<<<nd_blocks, 256, 0, stream>>>(hout[2], batch, psum, pmax, cnt, N);
    k_build_z<<<(G * DD + 255) / 256, 256, 0, stream>>>(psum, pmax, cnt, z, G);

    // head
    k_head<<<G, 128, 0, stream>>>(z, W1, b1, ln1g, ln1b, W2, b2, ln2g, ln2b, W3, b3, out);
}

// Round 3
// 1565.086 us; speedup vs baseline: 1.2248x; 1.2248x over previous
//
#include <hip/hip_runtime.h>
#include <hip/hip_bf16.h>

#define DD 64
#define EPSV 1e-5f

static __device__ __forceinline__ float fatomic_add(float* p, float v) {
#if defined(__HIP_DEVICE_COMPILE__)
    return unsafeAtomicAdd(p, v);
#else
    return 0.f;
#endif
}

static __device__ __forceinline__ float gelu_exact(float x) {
    return 0.5f * x * (1.0f + erff(x * 0.70710678118654752f));
}

// ---------------- CSR build ----------------
__global__ void k_hist(const int* __restrict__ dst, int* __restrict__ counts, int e) {
    int i = blockIdx.x * 256 + threadIdx.x;
    if (i < e) atomicAdd(&counts[dst[i]], 1);
}

// single-workgroup exclusive scan over counts[n] -> off[n+1]
__global__ __launch_bounds__(1024) void k_scan(const int* __restrict__ counts,
                                               int* __restrict__ off, int n, int etotal) {
    __shared__ int wpre[16];
    int t = threadIdx.x;
    int chunk = (n + 1023) >> 10;
    int s = t * chunk, e = min(s + chunk, n);
    int sum = 0;
    for (int i = s; i < e; ++i) sum += counts[i];
    int lane = t & 63, wv = t >> 6;
    int v = sum;
#pragma unroll
    for (int o = 1; o < 64; o <<= 1) {
        int u = __shfl_up(v, o, 64);
        if (lane >= o) v += u;
    }
    if (lane == 63) wpre[wv] = v;
    __syncthreads();
    if (t == 0) {
        int r = 0;
        for (int w = 0; w < 16; ++w) { int x = wpre[w]; wpre[w] = r; r += x; }
    }
    __syncthreads();
    int run = wpre[wv] + v - sum;  // exclusive prefix for this thread
    for (int i = s; i < e; ++i) { off[i] = run; run += counts[i]; }
    if (t == 0) off[n] = etotal;
}

__global__ void k_dinv_from_counts(const int* __restrict__ counts, float* __restrict__ dinv, int n) {
    int i = blockIdx.x * 256 + threadIdx.x;
    if (i < n) dinv[i] = rsqrtf((float)counts[i] + 1.0f);  // +1 self-loop
}

__global__ void k_copy_off(const int* __restrict__ off, int* __restrict__ cursor, int n) {
    int i = blockIdx.x * 256 + threadIdx.x;
    if (i < n) cursor[i] = off[i];
}

// csr entry: {src_index, dinv[src] as bits}
__global__ void k_fill(const int* __restrict__ src, const int* __restrict__ dst,
                       const float* __restrict__ dinv,
                       int* __restrict__ cursor, int2* __restrict__ csr, int e) {
    int i = blockIdx.x * 256 + threadIdx.x;
    if (i < e) {
        int d = dst[i];
        int s = src[i];
        int pos = atomicAdd(&cursor[d], 1);
        csr[pos] = make_int2(s, __float_as_int(dinv[s]));
    }
}

// ---------------- gather: P[d] = dinv[d]*(dinv[d]*h[d] + sum_e dinv[s]*h[s]) ----------------
__global__ __launch_bounds__(256) void k_gather(const int* __restrict__ off,
                                                const int2* __restrict__ csr,
                                                const float* __restrict__ dinv,
                                                const float* __restrict__ hin,
                                                float* __restrict__ P, int n) {
    int t = threadIdx.x;
    int lane = t & 63, wv = t >> 6;
    for (int node = blockIdx.x * 4 + wv; node < n; node += gridDim.x * 4) {
        int a = off[node], b = off[node + 1];
        float dd = dinv[node];
        float acc = dd * hin[(size_t)node * 64 + lane];  // self-loop
        for (int e = a; e < b; ++e) {
            int2 ent = csr[e];
            acc += __int_as_float(ent.y) * hin[(size_t)ent.x * 64 + lane];
        }
        P[(size_t)node * 64 + lane] = acc * dd;
    }
}

// ---------------- GEMM [n,64]@[64,64] + bias, in-place ok, fused BN col-stats ----------------
__global__ __launch_bounds__(256) void k_gemm_bias_stats(const float* __restrict__ P,
                                                         const float* __restrict__ W,
                                                         const float* __restrict__ convB,
                                                         float* __restrict__ agg,
                                                         float* __restrict__ gsum,
                                                         float* __restrict__ gsumsq, int n) {
    __shared__ float Wl[64 * 64];
    int t = threadIdx.x;
    for (int i = t; i < 64 * 64; i += 256) Wl[i] = W[i];
    __syncthreads();
    int lane = t & 63, wv = t >> 6;
    float bias = convB[lane];
    float s = 0.f, sq = 0.f;
    for (int r = blockIdx.x * 4 + wv; r < n; r += gridDim.x * 4) {
        float hv = P[(size_t)r * 64 + lane];
        float acc = bias;
#pragma unroll
        for (int k = 0; k < 64; ++k) {
            float a = __shfl(hv, k, 64);
            acc += a * Wl[k * 64 + lane];
        }
        agg[(size_t)r * 64 + lane] = acc;  // in-place over P is safe (row read before write)
        s += acc;
        sq += acc * acc;
    }
    __shared__ float ls[256], lq[256];
    ls[t] = s;
    lq[t] = sq;
    __syncthreads();
    if (t < 64) {
        float fs = ls[t] + ls[t + 64] + ls[t + 128] + ls[t + 192];
        float fq = lq[t] + lq[t + 64] + lq[t + 128] + lq[t + 192];
        fatomic_add(&gsum[t], fs);
        fatomic_add(&gsumsq[t], fq);
    }
}

// ---------------- BN + residual + LN + GELU (in-place over agg ok) ----------------
__global__ __launch_bounds__(256) void k_bn_ln_gelu(const float* __restrict__ agg,
                                                    const float* __restrict__ xin,
                                                    const float* __restrict__ gsum,
                                                    const float* __restrict__ gsumsq,
                                                    const float* __restrict__ bng,
                                                    const float* __restrict__ bnb,
                                                    const float* __restrict__ lng,
                                                    const float* __restrict__ lnb,
                                                    float* __restrict__ out, int n, int has_res) {
    int t = threadIdx.x;
    int lane = t & 63, wv = t >> 6;
    float invN = 1.0f / (float)n;
    float mu_c = gsum[lane] * invN;
    float var_c = gsumsq[lane] * invN - mu_c * mu_c;
    float bscale = rsqrtf(var_c + EPSV) * bng[lane];
    float bshift = bnb[lane];
    float lg = lng[lane], lb = lnb[lane];
    for (int r = blockIdx.x * 4 + wv; r < n; r += gridDim.x * 4) {
        float x = agg[(size_t)r * 64 + lane];
        float hb = (x - mu_c) * bscale + bshift;
        if (has_res) hb += xin[(size_t)r * 64 + lane];
        float ssum = hb;
#pragma unroll
        for (int off = 32; off; off >>= 1) ssum += __shfl_xor(ssum, off, 64);
        float rmu = ssum * (1.f / 64.f);
        float d = hb - rmu;
        float vs = d * d;
#pragma unroll
        for (int off = 32; off; off >>= 1) vs += __shfl_xor(vs, off, 64);
        float rvar = vs * (1.f / 64.f);
        float ln = d * rsqrtf(rvar + EPSV) * lg + lb;
        out[(size_t)r * 64 + lane] = gelu_exact(ln);
    }
}

// ---------------- pooling: one block per graph, batch is sorted ----------------
__global__ __launch_bounds__(64) void k_pool_z(const float* __restrict__ h,
                                               const int* __restrict__ batch,
                                               float* __restrict__ z, int n) {
    int g = blockIdx.x;
    int lane = threadIdx.x;
    int lo = 0, hi = n;
    while (lo < hi) { int m = (lo + hi) >> 1; if (batch[m] < g) lo = m + 1; else hi = m; }
    int s0 = lo;
    lo = 0; hi = n;
    while (lo < hi) { int m = (lo + hi) >> 1; if (batch[m] < g + 1) lo = m + 1; else hi = m; }
    int e0 = lo;
    float s = 0.f, mx = -INFINITY;
    for (int i = s0; i < e0; ++i) {
        float v = h[(size_t)i * 64 + lane];
        s += v;
        mx = fmaxf(mx, v);
    }
    float cntf = (float)(e0 - s0);
    float mean = s / fmaxf(cntf, 1.0f);
    if (e0 == s0) mx = 0.f;
    z[g * 192 + lane] = mean;
    z[g * 192 + 64 + lane] = mx;
    z[g * 192 + 128 + lane] = s;
}

// ---------------- MLP head (one block per graph) ----------------
__global__ __launch_bounds__(128) void k_head(const float* __restrict__ z,
                                              const float* __restrict__ W1, const float* __restrict__ b1,
                                              const float* __restrict__ ln1g, const float* __restrict__ ln1b,
                                              const float* __restrict__ W2, const float* __restrict__ b2,
                                              const float* __restrict__ ln2g, const float* __restrict__ ln2b,
                                              const float* __restrict__ W3, const float* __restrict__ b3,
                                              float* __restrict__ out) {
    int g = blockIdx.x;
    int t = threadIdx.x;
    int lane = t & 63, wv = t >> 6;
    __shared__ float zl[192], h1[128], red[2];
    for (int i = t; i < 192; i += 128) zl[i] = z[g * 192 + i];
    __syncthreads();
    float acc = b1[t];
    for (int k = 0; k < 192; ++k) acc += zl[k] * W1[k * 128 + t];
    float s = acc;
#pragma unroll
    for (int off = 32; off; off >>= 1) s += __shfl_xor(s, off, 64);
    if (lane == 0) red[wv] = s;
    __syncthreads();
    float mu = (red[0] + red[1]) * (1.f / 128.f);
    float d = acc - mu;
    float q = d * d;
#pragma unroll
    for (int off = 32; off; off >>= 1) q += __shfl_xor(q, off, 64);
    __syncthreads();
    if (lane == 0) red[wv] = q;
    __syncthreads();
    float var = (red[0] + red[1]) * (1.f / 128.f);
    float ln = d * rsqrtf(var + EPSV) * ln1g[t] + ln1b[t];
    h1[t] = gelu_exact(ln);
    __syncthreads();
    if (t < 64) {
        float acc2 = b2[t];
        for (int k = 0; k < 128; ++k) acc2 += h1[k] * W2[k * 64 + t];
        float s2 = acc2;
#pragma unroll
        for (int off = 32; off; off >>= 1) s2 += __shfl_xor(s2, off, 64);
        float mu2 = s2 * (1.f / 64.f);
        float d2 = acc2 - mu2;
        float q2 = d2 * d2;
#pragma unroll
        for (int off = 32; off; off >>= 1) q2 += __shfl_xor(q2, off, 64);
        float var2 = q2 * (1.f / 64.f);
        float l2 = d2 * rsqrtf(var2 + EPSV) * ln2g[t] + ln2b[t];
        float g2 = gelu_exact(l2);
        float p = g2 * W3[t];
#pragma unroll
        for (int off = 32; off; off >>= 1) p += __shfl_xor(p, off, 64);
        if (t == 0) out[g] = p + b3[0];
    }
}

extern "C" void kernel_launch(void* const* d_in, const int* in_sizes, int n_in,
                              void* d_out, int out_size, void* d_ws, size_t ws_size,
                              hipStream_t stream) {
    const float* x      = (const float*)d_in[0];
    const int*   eidx   = (const int*)d_in[1];
    const int*   batch  = (const int*)d_in[2];
    const float* convW  = (const float*)d_in[3];
    const float* convB  = (const float*)d_in[4];
    const float* bn_g   = (const float*)d_in[5];
    const float* bn_b   = (const float*)d_in[6];
    const float* ln_g   = (const float*)d_in[7];
    const float* ln_b   = (const float*)d_in[8];
    const float* W1     = (const float*)d_in[9];
    const float* b1     = (const float*)d_in[10];
    const float* ln1g   = (const float*)d_in[11];
    const float* ln1b   = (const float*)d_in[12];
    const float* W2     = (const float*)d_in[13];
    const float* b2     = (const float*)d_in[14];
    const float* ln2g   = (const float*)d_in[15];
    const float* ln2b   = (const float*)d_in[16];
    const float* W3     = (const float*)d_in[17];
    const float* b3     = (const float*)d_in[18];
    float* out = (float*)d_out;

    const int N = in_sizes[0] / DD;
    const int E = in_sizes[1] / 2;
    const int G = out_size;
    const int* esrc = eidx;
    const int* edst = eidx + E;

    char* ws = (char*)d_ws;
    size_t off_b = 0;
    auto alloc = [&](size_t bytes) {
        size_t p = off_b;
        off_b = (off_b + bytes + 255) & ~(size_t)255;
        return (void*)(ws + p);
    };
    // total: ~25.6*2 + 12.8 + ~1.7 MB ~= 65.7 MB (< the 78 MB footprint proven safe in R1)
    int*   counts = (int*)alloc((size_t)N * 4);   // reused as cursor after dinv computed
    int*   offs   = (int*)alloc((size_t)(N + 1) * 4);
    float* dinv   = (float*)alloc((size_t)N * 4);
    int2*  csr    = (int2*)alloc((size_t)E * 8);
    float* bufA   = (float*)alloc((size_t)N * DD * 4);
    float* bufB   = (float*)alloc((size_t)N * DD * 4);
    float* gstats = (float*)alloc(2 * DD * 4);
    float* gsum   = gstats;
    float* gsumsq = gstats + DD;
    float* z      = (float*)alloc((size_t)G * 3 * DD * 4);
    (void)ws_size; (void)n_in;

    // ---- CSR build (once per launch) ----
    hipMemsetAsync(counts, 0, (size_t)N * 4, stream);
    k_hist<<<(E + 255) / 256, 256, 0, stream>>>(edst, counts, E);
    k_scan<<<1, 1024, 0, stream>>>(counts, offs, N, E);
    k_dinv_from_counts<<<(N + 255) / 256, 256, 0, stream>>>(counts, dinv, N);
    k_copy_off<<<(N + 255) / 256, 256, 0, stream>>>(offs, counts, N);  // counts becomes cursor
    k_fill<<<(E + 255) / 256, 256, 0, stream>>>(esrc, edst, dinv, counts, csr, E);

    // buffer plan (aggregate-first, GEMM & BN/LN in-place):
    //   L0: hin=x  -> P=A -> agg=A -> hout=A
    //   L1: hin=A  -> P=B -> agg=B -> hout=B (residual reads A)
    //   L2: hin=B  -> P=A -> agg=A -> hout=A (residual reads B)
    const float* hin[3] = {x, bufA, bufB};
    float* Pb[3]  = {bufA, bufB, bufA};

    for (int l = 0; l < 3; ++l) {
        k_gather<<<1024, 256, 0, stream>>>(offs, csr, dinv, hin[l], Pb[l], N);
        hipMemsetAsync(gstats, 0, 2 * DD * 4, stream);
        k_gemm_bias_stats<<<1024, 256, 0, stream>>>(Pb[l], convW + (size_t)l * DD * DD,
                                                    convB + l * DD, Pb[l], gsum, gsumsq, N);
        k_bn_ln_gelu<<<1024, 256, 0, stream>>>(Pb[l], hin[l], gsum, gsumsq,
                                               bn_g + l * DD, bn_b + l * DD,
                                               ln_g + l * DD, ln_b + l * DD,
                                               Pb[l], N, l > 0 ? 1 : 0);
    }

    k_pool_z<<<G, 64, 0, stream>>>(bufA, batch, z, N);
    k_head<<<G, 128, 0, stream>>>(z, W1, b1, ln1g, ln1b, W2, b2, ln2g, ln2b, W3, b3, out);
}

// Round 4
// 1123.780 us; speedup vs baseline: 1.7057x; 1.3927x over previous
//
#include <hip/hip_runtime.h>
#include <hip/hip_bf16.h>

#define DD 64
#define EPSV 1e-5f

static __device__ __forceinline__ float fatomic_add(float* p, float v) {
#if defined(__HIP_DEVICE_COMPILE__)
    return unsafeAtomicAdd(p, v);
#else
    return 0.f;
#endif
}

static __device__ __forceinline__ float gelu_exact(float x) {
    return 0.5f * x * (1.0f + erff(x * 0.70710678118654752f));
}

// ---------------- CSR build ----------------
__global__ void k_hist(const int* __restrict__ dst, int* __restrict__ counts, int e) {
    int i = blockIdx.x * 256 + threadIdx.x;
    if (i < e) atomicAdd(&counts[dst[i]], 1);
}

// single-workgroup tiled scan, coalesced: counts[n] -> off[n+1] (exclusive)
__global__ __launch_bounds__(1024) void k_scan(const int* __restrict__ counts,
                                               int* __restrict__ off, int n, int etotal) {
    __shared__ int wsum[16];
    __shared__ int carry_s, tile_tot;
    int t = threadIdx.x;
    int lane = t & 63, wv = t >> 6;
    if (t == 0) carry_s = 0;
    __syncthreads();
    for (int base = 0; base < n; base += 1024) {
        int i = base + t;
        int v = (i < n) ? counts[i] : 0;
        int x = v;
#pragma unroll
        for (int o = 1; o < 64; o <<= 1) {
            int u = __shfl_up(x, o, 64);
            if (lane >= o) x += u;
        }
        if (lane == 63) wsum[wv] = x;
        __syncthreads();
        if (t == 0) {
            int r = 0;
#pragma unroll
            for (int w = 0; w < 16; ++w) { int y = wsum[w]; wsum[w] = r; r += y; }
            tile_tot = r;
        }
        __syncthreads();
        int excl = carry_s + wsum[wv] + x - v;
        if (i < n) off[i] = excl;
        __syncthreads();
        if (t == 0) carry_s += tile_tot;
        __syncthreads();
    }
    if (t == 0) off[n] = etotal;
}

__global__ void k_dinv_from_counts(const int* __restrict__ counts, float* __restrict__ dinv, int n) {
    int i = blockIdx.x * 256 + threadIdx.x;
    if (i < n) dinv[i] = rsqrtf((float)counts[i] + 1.0f);  // +1 self-loop
}

__global__ void k_copy_off(const int* __restrict__ off, int* __restrict__ cursor, int n) {
    int i = blockIdx.x * 256 + threadIdx.x;
    if (i < n) cursor[i] = off[i];
}

// csr entry: {src_index, dinv[src] as bits}
__global__ void k_fill(const int* __restrict__ src, const int* __restrict__ dst,
                       const float* __restrict__ dinv,
                       int* __restrict__ cursor, int2* __restrict__ csr, int e) {
    int i = blockIdx.x * 256 + threadIdx.x;
    if (i < e) {
        int d = dst[i];
        int s = src[i];
        int pos = atomicAdd(&cursor[d], 1);
        csr[pos] = make_int2(s, __float_as_int(dinv[s]));
    }
}

// ---------------- fused: gather (S@h) -> row GEMM (@W + b) -> BN col stats ----------------
// agg[d,:] = (dinv[d]*(dinv[d]*h[d,:] + sum_e dinv[s]*h[s,:])) @ W + convB
__global__ __launch_bounds__(256) void k_gather_gemm(const int* __restrict__ off,
                                                     const int2* __restrict__ csr,
                                                     const float* __restrict__ dinv,
                                                     const float* __restrict__ hin,
                                                     const float* __restrict__ W,
                                                     const float* __restrict__ convB,
                                                     float* __restrict__ agg,
                                                     float* __restrict__ gsum,
                                                     float* __restrict__ gsumsq, int n) {
    __shared__ float Wl[64 * 64];
    int t = threadIdx.x;
    for (int i = t; i < 64 * 64; i += 256) Wl[i] = W[i];
    int lane = t & 63, wv = t >> 6;
    float bias = convB[lane];
    float s = 0.f, sq = 0.f;
    __syncthreads();
    for (int node = blockIdx.x * 4 + wv; node < n; node += gridDim.x * 4) {
        int a = off[node], b = off[node + 1];
        float dd = dinv[node];
        float acc = dd * hin[(size_t)node * 64 + lane];  // self-loop
        for (int base = a; base < b; base += 64) {
            int rem = b - base;
            int cnt = rem < 64 ? rem : 64;
            int2 ent = make_int2(0, 0);
            if (lane < cnt) ent = csr[base + lane];  // wave-cooperative edge prefetch
            for (int j = 0; j < cnt; ++j) {
                int sn = __shfl(ent.x, j, 64);
                float w = __int_as_float(__shfl(ent.y, j, 64));
                acc += w * hin[(size_t)sn * 64 + lane];
            }
        }
        acc *= dd;
        // row GEMM via shuffle broadcast, 4-way split accumulators
        float r0 = bias, r1 = 0.f, r2 = 0.f, r3 = 0.f;
#pragma unroll
        for (int k = 0; k < 64; k += 4) {
            r0 += __shfl(acc, k, 64) * Wl[k * 64 + lane];
            r1 += __shfl(acc, k + 1, 64) * Wl[(k + 1) * 64 + lane];
            r2 += __shfl(acc, k + 2, 64) * Wl[(k + 2) * 64 + lane];
            r3 += __shfl(acc, k + 3, 64) * Wl[(k + 3) * 64 + lane];
        }
        float r = (r0 + r1) + (r2 + r3);
        agg[(size_t)node * 64 + lane] = r;
        s += r;
        sq += r * r;
    }
    __shared__ float ls[256], lq[256];
    ls[t] = s;
    lq[t] = sq;
    __syncthreads();
    if (t < 64) {
        float fs = ls[t] + ls[t + 64] + ls[t + 128] + ls[t + 192];
        float fq = lq[t] + lq[t + 64] + lq[t + 128] + lq[t + 192];
        fatomic_add(&gsum[t], fs);
        fatomic_add(&gsumsq[t], fq);
    }
}

// ---------------- BN + residual + LN + GELU (in-place over agg ok) ----------------
__global__ __launch_bounds__(256) void k_bn_ln_gelu(const float* __restrict__ agg,
                                                    const float* __restrict__ xin,
                                                    const float* __restrict__ gsum,
                                                    const float* __restrict__ gsumsq,
                                                    const float* __restrict__ bng,
                                                    const float* __restrict__ bnb,
                                                    const float* __restrict__ lng,
                                                    const float* __restrict__ lnb,
                                                    float* __restrict__ out, int n, int has_res) {
    int t = threadIdx.x;
    int lane = t & 63, wv = t >> 6;
    float invN = 1.0f / (float)n;
    float mu_c = gsum[lane] * invN;
    float var_c = gsumsq[lane] * invN - mu_c * mu_c;
    float bscale = rsqrtf(var_c + EPSV) * bng[lane];
    float bshift = bnb[lane];
    float lg = lng[lane], lb = lnb[lane];
    for (int r = blockIdx.x * 4 + wv; r < n; r += gridDim.x * 4) {
        float x = agg[(size_t)r * 64 + lane];
        float hb = (x - mu_c) * bscale + bshift;
        if (has_res) hb += xin[(size_t)r * 64 + lane];
        float ssum = hb;
#pragma unroll
        for (int off = 32; off; off >>= 1) ssum += __shfl_xor(ssum, off, 64);
        float rmu = ssum * (1.f / 64.f);
        float d = hb - rmu;
        float vs = d * d;
#pragma unroll
        for (int off = 32; off; off >>= 1) vs += __shfl_xor(vs, off, 64);
        float rvar = vs * (1.f / 64.f);
        float ln = d * rsqrtf(rvar + EPSV) * lg + lb;
        out[(size_t)r * 64 + lane] = gelu_exact(ln);
    }
}

// ---------------- pooling: one block per graph, batch is sorted ----------------
__global__ __launch_bounds__(64) void k_pool_z(const float* __restrict__ h,
                                               const int* __restrict__ batch,
                                               float* __restrict__ z, int n) {
    int g = blockIdx.x;
    int lane = threadIdx.x;
    int lo = 0, hi = n;
    while (lo < hi) { int m = (lo + hi) >> 1; if (batch[m] < g) lo = m + 1; else hi = m; }
    int s0 = lo;
    lo = 0; hi = n;
    while (lo < hi) { int m = (lo + hi) >> 1; if (batch[m] < g + 1) lo = m + 1; else hi = m; }
    int e0 = lo;
    float s = 0.f, mx = -INFINITY;
    for (int i = s0; i < e0; ++i) {
        float v = h[(size_t)i * 64 + lane];
        s += v;
        mx = fmaxf(mx, v);
    }
    float cntf = (float)(e0 - s0);
    float mean = s / fmaxf(cntf, 1.0f);
    if (e0 == s0) mx = 0.f;
    z[g * 192 + lane] = mean;
    z[g * 192 + 64 + lane] = mx;
    z[g * 192 + 128 + lane] = s;
}

// ---------------- MLP head (one block per graph) ----------------
__global__ __launch_bounds__(128) void k_head(const float* __restrict__ z,
                                              const float* __restrict__ W1, const float* __restrict__ b1,
                                              const float* __restrict__ ln1g, const float* __restrict__ ln1b,
                                              const float* __restrict__ W2, const float* __restrict__ b2,
                                              const float* __restrict__ ln2g, const float* __restrict__ ln2b,
                                              const float* __restrict__ W3, const float* __restrict__ b3,
                                              float* __restrict__ out) {
    int g = blockIdx.x;
    int t = threadIdx.x;
    int lane = t & 63, wv = t >> 6;
    __shared__ float zl[192], h1[128], red[2];
    for (int i = t; i < 192; i += 128) zl[i] = z[g * 192 + i];
    __syncthreads();
    float acc = b1[t];
    for (int k = 0; k < 192; ++k) acc += zl[k] * W1[k * 128 + t];
    float s = acc;
#pragma unroll
    for (int off = 32; off; off >>= 1) s += __shfl_xor(s, off, 64);
    if (lane == 0) red[wv] = s;
    __syncthreads();
    float mu = (red[0] + red[1]) * (1.f / 128.f);
    float d = acc - mu;
    float q = d * d;
#pragma unroll
    for (int off = 32; off; off >>= 1) q += __shfl_xor(q, off, 64);
    __syncthreads();
    if (lane == 0) red[wv] = q;
    __syncthreads();
    float var = (red[0] + red[1]) * (1.f / 128.f);
    float ln = d * rsqrtf(var + EPSV) * ln1g[t] + ln1b[t];
    h1[t] = gelu_exact(ln);
    __syncthreads();
    if (t < 64) {
        float acc2 = b2[t];
        for (int k = 0; k < 128; ++k) acc2 += h1[k] * W2[k * 64 + t];
        float s2 = acc2;
#pragma unroll
        for (int off = 32; off; off >>= 1) s2 += __shfl_xor(s2, off, 64);
        float mu2 = s2 * (1.f / 64.f);
        float d2 = acc2 - mu2;
        float q2 = d2 * d2;
#pragma unroll
        for (int off = 32; off; off >>= 1) q2 += __shfl_xor(q2, off, 64);
        float var2 = q2 * (1.f / 64.f);
        float l2 = d2 * rsqrtf(var2 + EPSV) * ln2g[t] + ln2b[t];
        float g2 = gelu_exact(l2);
        float p = g2 * W3[t];
#pragma unroll
        for (int off = 32; off; off >>= 1) p += __shfl_xor(p, off, 64);
        if (t == 0) out[g] = p + b3[0];
    }
}

extern "C" void kernel_launch(void* const* d_in, const int* in_sizes, int n_in,
                              void* d_out, int out_size, void* d_ws, size_t ws_size,
                              hipStream_t stream) {
    const float* x      = (const float*)d_in[0];
    const int*   eidx   = (const int*)d_in[1];
    const int*   batch  = (const int*)d_in[2];
    const float* convW  = (const float*)d_in[3];
    const float* convB  = (const float*)d_in[4];
    const float* bn_g   = (const float*)d_in[5];
    const float* bn_b   = (const float*)d_in[6];
    const float* ln_g   = (const float*)d_in[7];
    const float* ln_b   = (const float*)d_in[8];
    const float* W1     = (const float*)d_in[9];
    const float* b1     = (const float*)d_in[10];
    const float* ln1g   = (const float*)d_in[11];
    const float* ln1b   = (const float*)d_in[12];
    const float* W2     = (const float*)d_in[13];
    const float* b2     = (const float*)d_in[14];
    const float* ln2g   = (const float*)d_in[15];
    const float* ln2b   = (const float*)d_in[16];
    const float* W3     = (const float*)d_in[17];
    const float* b3     = (const float*)d_in[18];
    float* out = (float*)d_out;

    const int N = in_sizes[0] / DD;
    const int E = in_sizes[1] / 2;
    const int G = out_size;
    const int* esrc = eidx;
    const int* edst = eidx + E;

    char* ws = (char*)d_ws;
    size_t off_b = 0;
    auto alloc = [&](size_t bytes) {
        size_t p = off_b;
        off_b = (off_b + bytes + 255) & ~(size_t)255;
        return (void*)(ws + p);
    };
    // total ~= 65.7 MB (proven safe in R3)
    int*   counts = (int*)alloc((size_t)N * 4);   // reused as cursor
    int*   offs   = (int*)alloc((size_t)(N + 1) * 4);
    float* dinv   = (float*)alloc((size_t)N * 4);
    int2*  csr    = (int2*)alloc((size_t)E * 8);
    float* bufA   = (float*)alloc((size_t)N * DD * 4);
    float* bufB   = (float*)alloc((size_t)N * DD * 4);
    float* gstats = (float*)alloc(2 * DD * 4);
    float* gsum   = gstats;
    float* gsumsq = gstats + DD;
    float* z      = (float*)alloc((size_t)G * 3 * DD * 4);
    (void)ws_size; (void)n_in;

    // ---- CSR build (once per launch) ----
    hipMemsetAsync(counts, 0, (size_t)N * 4, stream);
    k_hist<<<(E + 255) / 256, 256, 0, stream>>>(edst, counts, E);
    k_scan<<<1, 1024, 0, stream>>>(counts, offs, N, E);
    k_dinv_from_counts<<<(N + 255) / 256, 256, 0, stream>>>(counts, dinv, N);
    k_copy_off<<<(N + 255) / 256, 256, 0, stream>>>(offs, counts, N);  // counts -> cursor
    k_fill<<<(E + 255) / 256, 256, 0, stream>>>(esrc, edst, dinv, counts, csr, E);

    // buffer plan (gather+gemm fused, BN/LN in-place):
    //   L0: hin=x  -> agg=A -> hout=A
    //   L1: hin=A  -> agg=B -> hout=B (residual A)
    //   L2: hin=B  -> agg=A -> hout=A (residual B)
    const float* hin[3] = {x, bufA, bufB};
    float* ag[3] = {bufA, bufB, bufA};

    for (int l = 0; l < 3; ++l) {
        hipMemsetAsync(gstats, 0, 2 * DD * 4, stream);
        k_gather_gemm<<<2048, 256, 0, stream>>>(offs, csr, dinv, hin[l],
                                                convW + (size_t)l * DD * DD, convB + l * DD,
                                                ag[l], gsum, gsumsq, N);
        k_bn_ln_gelu<<<2048, 256, 0, stream>>>(ag[l], hin[l], gsum, gsumsq,
                                               bn_g + l * DD, bn_b + l * DD,
                                               ln_g + l * DD, ln_b + l * DD,
                                               ag[l], N, l > 0 ? 1 : 0);
    }

    k_pool_z<<<G, 64, 0, stream>>>(bufA, batch, z, N);
    k_head<<<G, 128, 0, stream>>>(z, W1, b1, ln1g, ln1b, W2, b2, ln2g, ln2b, W3, b3, out);
}

// Round 5
// 881.657 us; speedup vs baseline: 2.1741x; 1.2746x over previous
//
#include <hip/hip_runtime.h>
#include <hip/hip_bf16.h>

#define DD 64
#define EPSV 1e-5f

static __device__ __forceinline__ float fatomic_add(float* p, float v) {
#if defined(__HIP_DEVICE_COMPILE__)
    return unsafeAtomicAdd(p, v);
#else
    return 0.f;
#endif
}

static __device__ __forceinline__ float gelu_exact(float x) {
    return 0.5f * x * (1.0f + erff(x * 0.70710678118654752f));
}

// ---------------- CSR build ----------------
__global__ void k_hist(const int* __restrict__ dst, int* __restrict__ counts, int e) {
    int i = blockIdx.x * 256 + threadIdx.x;
    if (i < e) atomicAdd(&counts[dst[i]], 1);
}

// single-workgroup tiled scan, coalesced: counts[n] -> off[n+1] (exclusive)
__global__ __launch_bounds__(1024) void k_scan(const int* __restrict__ counts,
                                               int* __restrict__ off, int n, int etotal) {
    __shared__ int wsum[16];
    __shared__ int carry_s, tile_tot;
    int t = threadIdx.x;
    int lane = t & 63, wv = t >> 6;
    if (t == 0) carry_s = 0;
    __syncthreads();
    for (int base = 0; base < n; base += 1024) {
        int i = base + t;
        int v = (i < n) ? counts[i] : 0;
        int x = v;
#pragma unroll
        for (int o = 1; o < 64; o <<= 1) {
            int u = __shfl_up(x, o, 64);
            if (lane >= o) x += u;
        }
        if (lane == 63) wsum[wv] = x;
        __syncthreads();
        if (t == 0) {
            int r = 0;
#pragma unroll
            for (int w = 0; w < 16; ++w) { int y = wsum[w]; wsum[w] = r; r += y; }
            tile_tot = r;
        }
        __syncthreads();
        int excl = carry_s + wsum[wv] + x - v;
        if (i < n) off[i] = excl;
        __syncthreads();
        if (t == 0) carry_s += tile_tot;
        __syncthreads();
    }
    if (t == 0) off[n] = etotal;
}

__global__ void k_dinv_from_counts(const int* __restrict__ counts, float* __restrict__ dinv, int n) {
    int i = blockIdx.x * 256 + threadIdx.x;
    if (i < n) dinv[i] = rsqrtf((float)counts[i] + 1.0f);  // +1 self-loop
}

__global__ void k_copy_off(const int* __restrict__ off, int* __restrict__ cursor, int n) {
    int i = blockIdx.x * 256 + threadIdx.x;
    if (i < n) cursor[i] = off[i];
}

// csr entry: {src_index, dinv[src] as bits}
__global__ void k_fill(const int* __restrict__ src, const int* __restrict__ dst,
                       const float* __restrict__ dinv,
                       int* __restrict__ cursor, int2* __restrict__ csr, int e) {
    int i = blockIdx.x * 256 + threadIdx.x;
    if (i < e) {
        int d = dst[i];
        int s = src[i];
        int pos = atomicAdd(&cursor[d], 1);
        csr[pos] = make_int2(s, __float_as_int(dinv[s]));
    }
}

// ---------------- fused: float4 quadrant gather -> row GEMM -> BN col stats ----------------
// agg[d,:] = (dinv[d]*(dinv[d]*h[d,:] + sum_e dinv[s]*h[s,:])) @ W + convB
__global__ __launch_bounds__(256) void k_gather_gemm(const int* __restrict__ off,
                                                     const int2* __restrict__ csr,
                                                     const float* __restrict__ dinv,
                                                     const float* __restrict__ hin,
                                                     const float* __restrict__ W,
                                                     const float* __restrict__ convB,
                                                     float* __restrict__ agg,
                                                     float* __restrict__ gsum,
                                                     float* __restrict__ gsumsq, int n) {
    __shared__ float Wl[64 * 64];
    int t = threadIdx.x;
    for (int i = t; i < 64 * 64; i += 256) Wl[i] = W[i];
    int lane = t & 63, wv = t >> 6;
    int qd = lane >> 4;    // quadrant: which edge of a 4-group this lane gathers
    int sub = lane & 15;   // which float4 of the row
    const float4* hin4 = (const float4*)hin;
    float bias = convB[lane];
    float s = 0.f, sq = 0.f;
    __syncthreads();
    for (int node = blockIdx.x * 4 + wv; node < n; node += gridDim.x * 4) {
        int a = off[node], b = off[node + 1];
        float dd = dinv[node];
        float ax = 0.f, ay = 0.f, az = 0.f, aw = 0.f;
        for (int base = a; base < b; base += 64) {
            int rem = b - base;
            int cnt = rem < 64 ? rem : 64;
            int2 ent = make_int2(0, 0);  // zero-fill => tail lanes contribute w=0 on row 0
            if (lane < cnt) ent = csr[base + lane];
            for (int jj = 0; jj < cnt; jj += 4) {
                int j = jj + qd;  // <= 63 always
                int sn = __shfl(ent.x, j, 64);
                float w = __int_as_float(__shfl(ent.y, j, 64));
                float4 hv = hin4[(size_t)sn * 16 + sub];
                ax += w * hv.x;
                ay += w * hv.y;
                az += w * hv.z;
                aw += w * hv.w;
            }
        }
        // combine quadrants: after this, every lane holds column sums for cols 4*sub..+3
        ax += __shfl_xor(ax, 16, 64); ax += __shfl_xor(ax, 32, 64);
        ay += __shfl_xor(ay, 16, 64); ay += __shfl_xor(ay, 32, 64);
        az += __shfl_xor(az, 16, 64); az += __shfl_xor(az, 32, 64);
        aw += __shfl_xor(aw, 16, 64); aw += __shfl_xor(aw, 32, 64);
        // self-loop + outer dinv scale
        float4 hs = hin4[(size_t)node * 16 + sub];
        ax = (ax + dd * hs.x) * dd;
        ay = (ay + dd * hs.y) * dd;
        az = (az + dd * hs.z) * dd;
        aw = (aw + dd * hs.w) * dd;
        // row GEMM: column k's value lives in component (k&3) of lane (k>>2)
        float r0 = bias, r1 = 0.f, r2 = 0.f, r3 = 0.f;
#pragma unroll
        for (int kk = 0; kk < 16; ++kk) {
            float a0 = __shfl(ax, kk, 64);
            float a1 = __shfl(ay, kk, 64);
            float a2 = __shfl(az, kk, 64);
            float a3 = __shfl(aw, kk, 64);
            r0 += a0 * Wl[(4 * kk + 0) * 64 + lane];
            r1 += a1 * Wl[(4 * kk + 1) * 64 + lane];
            r2 += a2 * Wl[(4 * kk + 2) * 64 + lane];
            r3 += a3 * Wl[(4 * kk + 3) * 64 + lane];
        }
        float r = (r0 + r1) + (r2 + r3);
        agg[(size_t)node * 64 + lane] = r;
        s += r;
        sq += r * r;
    }
    __shared__ float ls[256], lq[256];
    ls[t] = s;
    lq[t] = sq;
    __syncthreads();
    if (t < 64) {
        float fs = ls[t] + ls[t + 64] + ls[t + 128] + ls[t + 192];
        float fq = lq[t] + lq[t + 64] + lq[t + 128] + lq[t + 192];
        fatomic_add(&gsum[t], fs);
        fatomic_add(&gsumsq[t], fq);
    }
}

// ---------------- BN + residual + LN + GELU (in-place over agg ok) ----------------
__global__ __launch_bounds__(256) void k_bn_ln_gelu(const float* __restrict__ agg,
                                                    const float* __restrict__ xin,
                                                    const float* __restrict__ gsum,
                                                    const float* __restrict__ gsumsq,
                                                    const float* __restrict__ bng,
                                                    const float* __restrict__ bnb,
                                                    const float* __restrict__ lng,
                                                    const float* __restrict__ lnb,
                                                    float* __restrict__ out, int n, int has_res) {
    int t = threadIdx.x;
    int lane = t & 63, wv = t >> 6;
    float invN = 1.0f / (float)n;
    float mu_c = gsum[lane] * invN;
    float var_c = gsumsq[lane] * invN - mu_c * mu_c;
    float bscale = rsqrtf(var_c + EPSV) * bng[lane];
    float bshift = bnb[lane];
    float lg = lng[lane], lb = lnb[lane];
    for (int r = blockIdx.x * 4 + wv; r < n; r += gridDim.x * 4) {
        float x = agg[(size_t)r * 64 + lane];
        float hb = (x - mu_c) * bscale + bshift;
        if (has_res) hb += xin[(size_t)r * 64 + lane];
        float ssum = hb;
#pragma unroll
        for (int off = 32; off; off >>= 1) ssum += __shfl_xor(ssum, off, 64);
        float rmu = ssum * (1.f / 64.f);
        float d = hb - rmu;
        float vs = d * d;
#pragma unroll
        for (int off = 32; off; off >>= 1) vs += __shfl_xor(vs, off, 64);
        float rvar = vs * (1.f / 64.f);
        float ln = d * rsqrtf(rvar + EPSV) * lg + lb;
        out[(size_t)r * 64 + lane] = gelu_exact(ln);
    }
}

// ---------------- pooling: one block per graph, batch is sorted ----------------
__global__ __launch_bounds__(64) void k_pool_z(const float* __restrict__ h,
                                               const int* __restrict__ batch,
                                               float* __restrict__ z, int n) {
    int g = blockIdx.x;
    int lane = threadIdx.x;
    int lo = 0, hi = n;
    while (lo < hi) { int m = (lo + hi) >> 1; if (batch[m] < g) lo = m + 1; else hi = m; }
    int s0 = lo;
    lo = 0; hi = n;
    while (lo < hi) { int m = (lo + hi) >> 1; if (batch[m] < g + 1) lo = m + 1; else hi = m; }
    int e0 = lo;
    float s = 0.f, mx = -INFINITY;
    for (int i = s0; i < e0; ++i) {
        float v = h[(size_t)i * 64 + lane];
        s += v;
        mx = fmaxf(mx, v);
    }
    float cntf = (float)(e0 - s0);
    float mean = s / fmaxf(cntf, 1.0f);
    if (e0 == s0) mx = 0.f;
    z[g * 192 + lane] = mean;
    z[g * 192 + 64 + lane] = mx;
    z[g * 192 + 128 + lane] = s;
}

// ---------------- MLP head (one block per graph) ----------------
__global__ __launch_bounds__(128) void k_head(const float* __restrict__ z,
                                              const float* __restrict__ W1, const float* __restrict__ b1,
                                              const float* __restrict__ ln1g, const float* __restrict__ ln1b,
                                              const float* __restrict__ W2, const float* __restrict__ b2,
                                              const float* __restrict__ ln2g, const float* __restrict__ ln2b,
                                              const float* __restrict__ W3, const float* __restrict__ b3,
                                              float* __restrict__ out) {
    int g = blockIdx.x;
    int t = threadIdx.x;
    int lane = t & 63, wv = t >> 6;
    __shared__ float zl[192], h1[128], red[2];
    for (int i = t; i < 192; i += 128) zl[i] = z[g * 192 + i];
    __syncthreads();
    float acc = b1[t];
    for (int k = 0; k < 192; ++k) acc += zl[k] * W1[k * 128 + t];
    float s = acc;
#pragma unroll
    for (int off = 32; off; off >>= 1) s += __shfl_xor(s, off, 64);
    if (lane == 0) red[wv] = s;
    __syncthreads();
    float mu = (red[0] + red[1]) * (1.f / 128.f);
    float d = acc - mu;
    float q = d * d;
#pragma unroll
    for (int off = 32; off; off >>= 1) q += __shfl_xor(q, off, 64);
    __syncthreads();
    if (lane == 0) red[wv] = q;
    __syncthreads();
    float var = (red[0] + red[1]) * (1.f / 128.f);
    float ln = d * rsqrtf(var + EPSV) * ln1g[t] + ln1b[t];
    h1[t] = gelu_exact(ln);
    __syncthreads();
    if (t < 64) {
        float acc2 = b2[t];
        for (int k = 0; k < 128; ++k) acc2 += h1[k] * W2[k * 64 + t];
        float s2 = acc2;
#pragma unroll
        for (int off = 32; off; off >>= 1) s2 += __shfl_xor(s2, off, 64);
        float mu2 = s2 * (1.f / 64.f);
        float d2 = acc2 - mu2;
        float q2 = d2 * d2;
#pragma unroll
        for (int off = 32; off; off >>= 1) q2 += __shfl_xor(q2, off, 64);
        float var2 = q2 * (1.f / 64.f);
        float l2 = d2 * rsqrtf(var2 + EPSV) * ln2g[t] + ln2b[t];
        float g2 = gelu_exact(l2);
        float p = g2 * W3[t];
#pragma unroll
        for (int off = 32; off; off >>= 1) p += __shfl_xor(p, off, 64);
        if (t == 0) out[g] = p + b3[0];
    }
}

extern "C" void kernel_launch(void* const* d_in, const int* in_sizes, int n_in,
                              void* d_out, int out_size, void* d_ws, size_t ws_size,
                              hipStream_t stream) {
    const float* x      = (const float*)d_in[0];
    const int*   eidx   = (const int*)d_in[1];
    const int*   batch  = (const int*)d_in[2];
    const float* convW  = (const float*)d_in[3];
    const float* convB  = (const float*)d_in[4];
    const float* bn_g   = (const float*)d_in[5];
    const float* bn_b   = (const float*)d_in[6];
    const float* ln_g   = (const float*)d_in[7];
    const float* ln_b   = (const float*)d_in[8];
    const float* W1     = (const float*)d_in[9];
    const float* b1     = (const float*)d_in[10];
    const float* ln1g   = (const float*)d_in[11];
    const float* ln1b   = (const float*)d_in[12];
    const float* W2     = (const float*)d_in[13];
    const float* b2     = (const float*)d_in[14];
    const float* ln2g   = (const float*)d_in[15];
    const float* ln2b   = (const float*)d_in[16];
    const float* W3     = (const float*)d_in[17];
    const float* b3     = (const float*)d_in[18];
    float* out = (float*)d_out;

    const int N = in_sizes[0] / DD;
    const int E = in_sizes[1] / 2;
    const int G = out_size;
    const int* esrc = eidx;
    const int* edst = eidx + E;

    char* ws = (char*)d_ws;
    size_t off_b = 0;
    auto alloc = [&](size_t bytes) {
        size_t p = off_b;
        off_b = (off_b + bytes + 255) & ~(size_t)255;
        return (void*)(ws + p);
    };
    // total ~= 65.7 MB (proven safe)
    int*   counts = (int*)alloc((size_t)N * 4);   // reused as cursor
    int*   offs   = (int*)alloc((size_t)(N + 1) * 4);
    float* dinv   = (float*)alloc((size_t)N * 4);
    int2*  csr    = (int2*)alloc((size_t)E * 8);
    float* bufA   = (float*)alloc((size_t)N * DD * 4);
    float* bufB   = (float*)alloc((size_t)N * DD * 4);
    float* gstats = (float*)alloc(2 * DD * 4);
    float* gsum   = gstats;
    float* gsumsq = gstats + DD;
    float* z      = (float*)alloc((size_t)G * 3 * DD * 4);
    (void)ws_size; (void)n_in;

    // ---- CSR build (once per launch) ----
    hipMemsetAsync(counts, 0, (size_t)N * 4, stream);
    k_hist<<<(E + 255) / 256, 256, 0, stream>>>(edst, counts, E);
    k_scan<<<1, 1024, 0, stream>>>(counts, offs, N, E);
    k_dinv_from_counts<<<(N + 255) / 256, 256, 0, stream>>>(counts, dinv, N);
    k_copy_off<<<(N + 255) / 256, 256, 0, stream>>>(offs, counts, N);  // counts -> cursor
    k_fill<<<(E + 255) / 256, 256, 0, stream>>>(esrc, edst, dinv, counts, csr, E);

    // buffer plan:
    //   L0: hin=x  -> agg=A -> hout=A
    //   L1: hin=A  -> agg=B -> hout=B (residual A)
    //   L2: hin=B  -> agg=A -> hout=A (residual B)
    const float* hin[3] = {x, bufA, bufB};
    float* ag[3] = {bufA, bufB, bufA};

    for (int l = 0; l < 3; ++l) {
        hipMemsetAsync(gstats, 0, 2 * DD * 4, stream);
        k_gather_gemm<<<2048, 256, 0, stream>>>(offs, csr, dinv, hin[l],
                                                convW + (size_t)l * DD * DD, convB + l * DD,
                                                ag[l], gsum, gsumsq, N);
        k_bn_ln_gelu<<<2048, 256, 0, stream>>>(ag[l], hin[l], gsum, gsumsq,
                                               bn_g + l * DD, bn_b + l * DD,
                                               ln_g + l * DD, ln_b + l * DD,
                                               ag[l], N, l > 0 ? 1 : 0);
    }

    k_pool_z<<<G, 64, 0, stream>>>(bufA, batch, z, N);
    k_head<<<G, 128, 0, stream>>>(z, W1, b1, ln1g, ln1b, W2, b2, ln2g, ln2b, W3, b3, out);
}

// Round 6
// 869.142 us; speedup vs baseline: 2.2054x; 1.0144x over previous
//
#include <hip/hip_runtime.h>
#include <hip/hip_bf16.h>
#include <hip/hip_fp16.h>

#define DD 64
#define EPSV 1e-5f

static __device__ __forceinline__ float fatomic_add(float* p, float v) {
#if defined(__HIP_DEVICE_COMPILE__)
    return unsafeAtomicAdd(p, v);
#else
    return 0.f;
#endif
}

static __device__ __forceinline__ float gelu_exact(float x) {
    return 0.5f * x * (1.0f + erff(x * 0.70710678118654752f));
}

// ---------------- CSR build ----------------
__global__ void k_hist(const int* __restrict__ dst, int* __restrict__ counts, int e) {
    int i = blockIdx.x * 256 + threadIdx.x;
    if (i < e) atomicAdd(&counts[dst[i]], 1);
}

// single-workgroup tiled scan, fused: counts[n] -> off[n+1] (exclusive),
// dinv[i] = rsqrt(counts[i]+1), cursor written IN-PLACE over counts.
__global__ __launch_bounds__(1024) void k_scan_fused(int* __restrict__ counts,
                                                     int* __restrict__ off,
                                                     float* __restrict__ dinv,
                                                     int n, int etotal) {
    __shared__ int wsum[16];
    __shared__ int carry_s, tile_tot;
    int t = threadIdx.x;
    int lane = t & 63, wv = t >> 6;
    if (t == 0) carry_s = 0;
    __syncthreads();
    for (int base = 0; base < n; base += 1024) {
        int i = base + t;
        int v = (i < n) ? counts[i] : 0;
        int x = v;
#pragma unroll
        for (int o = 1; o < 64; o <<= 1) {
            int u = __shfl_up(x, o, 64);
            if (lane >= o) x += u;
        }
        if (lane == 63) wsum[wv] = x;
        __syncthreads();
        if (t == 0) {
            int r = 0;
#pragma unroll
            for (int w = 0; w < 16; ++w) { int y = wsum[w]; wsum[w] = r; r += y; }
            tile_tot = r;
        }
        __syncthreads();
        int excl = carry_s + wsum[wv] + x - v;
        if (i < n) {
            off[i] = excl;
            dinv[i] = rsqrtf((float)v + 1.0f);  // +1 self-loop
            counts[i] = excl;                    // becomes cursor for k_fill
        }
        __syncthreads();
        if (t == 0) carry_s += tile_tot;
        __syncthreads();
    }
    if (t == 0) off[n] = etotal;
}

// csr entry: {src_index, dinv[src] as bits}
__global__ void k_fill(const int* __restrict__ src, const int* __restrict__ dst,
                       const float* __restrict__ dinv,
                       int* __restrict__ cursor, int2* __restrict__ csr, int e) {
    int i = blockIdx.x * 256 + threadIdx.x;
    if (i < e) {
        int d = dst[i];
        int s = src[i];
        int pos = atomicAdd(&cursor[d], 1);
        csr[pos] = make_int2(s, __float_as_int(dinv[s]));
    }
}

// ---------------- x -> fp16 mirror, plus zero gstats (3 layers x 128 floats) ----------------
__global__ void k_xtohalf(const float* __restrict__ x, __half* __restrict__ m,
                          int total, float* __restrict__ gstats) {
    int i = blockIdx.x * 256 + threadIdx.x;
    if (blockIdx.x == 0 && threadIdx.x < 384) gstats[threadIdx.x] = 0.f;
    if (i < total) m[i] = __float2half_rn(x[i]);
}

// ---------------- fused: fp16 8-edge gather -> row GEMM -> BN col stats ----------------
// agg[d,:] = (dinv[d]*(dinv[d]*h[d,:] + sum_e dinv[s]*h[s,:])) @ W + convB
__global__ __launch_bounds__(256) void k_gather_gemm(const int* __restrict__ off,
                                                     const int2* __restrict__ csr,
                                                     const float* __restrict__ dinv,
                                                     const uint4* __restrict__ m16,  // N rows x 8 chunks of 8 halfs
                                                     const float* __restrict__ W,
                                                     const float* __restrict__ convB,
                                                     float* __restrict__ agg,
                                                     float* __restrict__ gsum,
                                                     float* __restrict__ gsumsq, int n) {
    __shared__ float Wl[64 * 64];
    int t = threadIdx.x;
    for (int i = t; i < 64 * 64; i += 256) Wl[i] = W[i];
    int lane = t & 63, wv = t >> 6;
    int oct = lane >> 3;   // which edge of an 8-group this lane gathers
    int sub = lane & 7;    // which 16B chunk (8 cols) of the row
    float bias = convB[lane];
    float s = 0.f, sq = 0.f;
    __syncthreads();
    for (int node = blockIdx.x * 4 + wv; node < n; node += gridDim.x * 4) {
        int a = off[node], b = off[node + 1];
        float dd = dinv[node];
        float acc[8];
#pragma unroll
        for (int p = 0; p < 8; ++p) acc[p] = 0.f;
        for (int base = a; base < b; base += 64) {
            int rem = b - base;
            int cnt = rem < 64 ? rem : 64;
            int2 ent = make_int2(0, 0);  // zero-fill: tail lanes get w=0 on row 0
            if (lane < cnt) ent = csr[base + lane];
            for (int jj = 0; jj < cnt; jj += 8) {
                int j = jj + oct;  // <= 63 always
                int sn = __shfl(ent.x, j, 64);
                float w = __int_as_float(__shfl(ent.y, j, 64));
                uint4 v = m16[(size_t)sn * 8 + sub];
                const __half2* h2 = reinterpret_cast<const __half2*>(&v);
#pragma unroll
                for (int p = 0; p < 4; ++p) {
                    float2 f = __half22float2(h2[p]);
                    acc[2 * p]     += w * f.x;
                    acc[2 * p + 1] += w * f.y;
                }
            }
        }
        // reduce across octs: lanes with equal sub sum up
#pragma unroll
        for (int p = 0; p < 8; ++p) {
            acc[p] += __shfl_xor(acc[p], 8, 64);
            acc[p] += __shfl_xor(acc[p], 16, 64);
            acc[p] += __shfl_xor(acc[p], 32, 64);
        }
        // self-loop + outer dinv scale (cols 8*sub + p)
        {
            uint4 v = m16[(size_t)node * 8 + sub];
            const __half2* h2 = reinterpret_cast<const __half2*>(&v);
#pragma unroll
            for (int p = 0; p < 4; ++p) {
                float2 f = __half22float2(h2[p]);
                acc[2 * p]     = (acc[2 * p]     + dd * f.x) * dd;
                acc[2 * p + 1] = (acc[2 * p + 1] + dd * f.y) * dd;
            }
        }
        // row GEMM: column c's value is component (c&7) of lane (c>>3)
        float r0 = bias, r1 = 0.f, r2 = 0.f, r3 = 0.f;
#pragma unroll
        for (int c = 0; c < 64; c += 4) {
            r0 += __shfl(acc[(c + 0) & 7], (c + 0) >> 3, 64) * Wl[(c + 0) * 64 + lane];
            r1 += __shfl(acc[(c + 1) & 7], (c + 1) >> 3, 64) * Wl[(c + 1) * 64 + lane];
            r2 += __shfl(acc[(c + 2) & 7], (c + 2) >> 3, 64) * Wl[(c + 2) * 64 + lane];
            r3 += __shfl(acc[(c + 3) & 7], (c + 3) >> 3, 64) * Wl[(c + 3) * 64 + lane];
        }
        float r = (r0 + r1) + (r2 + r3);
        agg[(size_t)node * 64 + lane] = r;
        s += r;
        sq += r * r;
    }
    __shared__ float ls[256], lq[256];
    ls[t] = s;
    lq[t] = sq;
    __syncthreads();
    if (t < 64) {
        float fs = ls[t] + ls[t + 64] + ls[t + 128] + ls[t + 192];
        float fq = lq[t] + lq[t + 64] + lq[t + 128] + lq[t + 192];
        fatomic_add(&gsum[t], fs);
        fatomic_add(&gsumsq[t], fq);
    }
}

// ---------------- BN + residual + LN + GELU (+ fp16 mirror of output) ----------------
__global__ __launch_bounds__(256) void k_bn_ln_gelu(const float* __restrict__ agg,
                                                    const float* __restrict__ xin,
                                                    const float* __restrict__ gsum,
                                                    const float* __restrict__ gsumsq,
                                                    const float* __restrict__ bng,
                                                    const float* __restrict__ bnb,
                                                    const float* __restrict__ lng,
                                                    const float* __restrict__ lnb,
                                                    float* __restrict__ out,
                                                    __half* __restrict__ m16,
                                                    int n, int has_res, int write_m) {
    int t = threadIdx.x;
    int lane = t & 63, wv = t >> 6;
    float invN = 1.0f / (float)n;
    float mu_c = gsum[lane] * invN;
    float var_c = gsumsq[lane] * invN - mu_c * mu_c;
    float bscale = rsqrtf(var_c + EPSV) * bng[lane];
    float bshift = bnb[lane];
    float lg = lng[lane], lb = lnb[lane];
    for (int r = blockIdx.x * 4 + wv; r < n; r += gridDim.x * 4) {
        float x = agg[(size_t)r * 64 + lane];
        float hb = (x - mu_c) * bscale + bshift;
        if (has_res) hb += xin[(size_t)r * 64 + lane];
        float ssum = hb;
#pragma unroll
        for (int off = 32; off; off >>= 1) ssum += __shfl_xor(ssum, off, 64);
        float rmu = ssum * (1.f / 64.f);
        float d = hb - rmu;
        float vs = d * d;
#pragma unroll
        for (int off = 32; off; off >>= 1) vs += __shfl_xor(vs, off, 64);
        float rvar = vs * (1.f / 64.f);
        float ln = d * rsqrtf(rvar + EPSV) * lg + lb;
        float g = gelu_exact(ln);
        out[(size_t)r * 64 + lane] = g;
        if (write_m) m16[(size_t)r * 64 + lane] = __float2half_rn(g);
    }
}

// ---------------- pooling: one block per graph, batch is sorted ----------------
__global__ __launch_bounds__(64) void k_pool_z(const float* __restrict__ h,
                                               const int* __restrict__ batch,
                                               float* __restrict__ z, int n) {
    int g = blockIdx.x;
    int lane = threadIdx.x;
    int lo = 0, hi = n;
    while (lo < hi) { int m = (lo + hi) >> 1; if (batch[m] < g) lo = m + 1; else hi = m; }
    int s0 = lo;
    lo = 0; hi = n;
    while (lo < hi) { int m = (lo + hi) >> 1; if (batch[m] < g + 1) lo = m + 1; else hi = m; }
    int e0 = lo;
    float s = 0.f, mx = -INFINITY;
    for (int i = s0; i < e0; ++i) {
        float v = h[(size_t)i * 64 + lane];
        s += v;
        mx = fmaxf(mx, v);
    }
    float cntf = (float)(e0 - s0);
    float mean = s / fmaxf(cntf, 1.0f);
    if (e0 == s0) mx = 0.f;
    z[g * 192 + lane] = mean;
    z[g * 192 + 64 + lane] = mx;
    z[g * 192 + 128 + lane] = s;
}

// ---------------- MLP head (one block per graph) ----------------
__global__ __launch_bounds__(128) void k_head(const float* __restrict__ z,
                                              const float* __restrict__ W1, const float* __restrict__ b1,
                                              const float* __restrict__ ln1g, const float* __restrict__ ln1b,
                                              const float* __restrict__ W2, const float* __restrict__ b2,
                                              const float* __restrict__ ln2g, const float* __restrict__ ln2b,
                                              const float* __restrict__ W3, const float* __restrict__ b3,
                                              float* __restrict__ out) {
    int g = blockIdx.x;
    int t = threadIdx.x;
    int lane = t & 63, wv = t >> 6;
    __shared__ float zl[192], h1[128], red[2];
    for (int i = t; i < 192; i += 128) zl[i] = z[g * 192 + i];
    __syncthreads();
    float acc = b1[t];
    for (int k = 0; k < 192; ++k) acc += zl[k] * W1[k * 128 + t];
    float s = acc;
#pragma unroll
    for (int off = 32; off; off >>= 1) s += __shfl_xor(s, off, 64);
    if (lane == 0) red[wv] = s;
    __syncthreads();
    float mu = (red[0] + red[1]) * (1.f / 128.f);
    float d = acc - mu;
    float q = d * d;
#pragma unroll
    for (int off = 32; off; off >>= 1) q += __shfl_xor(q, off, 64);
    __syncthreads();
    if (lane == 0) red[wv] = q;
    __syncthreads();
    float var = (red[0] + red[1]) * (1.f / 128.f);
    float ln = d * rsqrtf(var + EPSV) * ln1g[t] + ln1b[t];
    h1[t] = gelu_exact(ln);
    __syncthreads();
    if (t < 64) {
        float acc2 = b2[t];
        for (int k = 0; k < 128; ++k) acc2 += h1[k] * W2[k * 64 + t];
        float s2 = acc2;
#pragma unroll
        for (int off = 32; off; off >>= 1) s2 += __shfl_xor(s2, off, 64);
        float mu2 = s2 * (1.f / 64.f);
        float d2 = acc2 - mu2;
        float q2 = d2 * d2;
#pragma unroll
        for (int off = 32; off; off >>= 1) q2 += __shfl_xor(q2, off, 64);
        float var2 = q2 * (1.f / 64.f);
        float l2 = d2 * rsqrtf(var2 + EPSV) * ln2g[t] + ln2b[t];
        float g2 = gelu_exact(l2);
        float p = g2 * W3[t];
#pragma unroll
        for (int off = 32; off; off >>= 1) p += __shfl_xor(p, off, 64);
        if (t == 0) out[g] = p + b3[0];
    }
}

extern "C" void kernel_launch(void* const* d_in, const int* in_sizes, int n_in,
                              void* d_out, int out_size, void* d_ws, size_t ws_size,
                              hipStream_t stream) {
    const float* x      = (const float*)d_in[0];
    const int*   eidx   = (const int*)d_in[1];
    const int*   batch  = (const int*)d_in[2];
    const float* convW  = (const float*)d_in[3];
    const float* convB  = (const float*)d_in[4];
    const float* bn_g   = (const float*)d_in[5];
    const float* bn_b   = (const float*)d_in[6];
    const float* ln_g   = (const float*)d_in[7];
    const float* ln_b   = (const float*)d_in[8];
    const float* W1     = (const float*)d_in[9];
    const float* b1     = (const float*)d_in[10];
    const float* ln1g   = (const float*)d_in[11];
    const float* ln1b   = (const float*)d_in[12];
    const float* W2     = (const float*)d_in[13];
    const float* b2     = (const float*)d_in[14];
    const float* ln2g   = (const float*)d_in[15];
    const float* ln2b   = (const float*)d_in[16];
    const float* W3     = (const float*)d_in[17];
    const float* b3     = (const float*)d_in[18];
    float* out = (float*)d_out;

    const int N = in_sizes[0] / DD;
    const int E = in_sizes[1] / 2;
    const int G = out_size;
    const int* esrc = eidx;
    const int* edst = eidx + E;

    char* ws = (char*)d_ws;
    size_t off_b = 0;
    auto alloc = [&](size_t bytes) {
        size_t p = off_b;
        off_b = (off_b + bytes + 255) & ~(size_t)255;
        return (void*)(ws + p);
    };
    // layout total ~77.6 MB (< 77.86 MB proven safe in R1):
    int*    offs   = (int*)alloc((size_t)(N + 1) * 4);
    float*  dinv   = (float*)alloc((size_t)N * 4);
    int2*   csr    = (int2*)alloc((size_t)E * 8);
    __half* m16    = (__half*)alloc((size_t)N * DD * 2);
    float*  bufA   = (float*)alloc((size_t)N * DD * 4);
    float*  bufB   = (float*)alloc((size_t)N * DD * 4);
    float*  gstats = (float*)alloc(3 * 2 * DD * 4);  // 3 layers x (gsum|gsumsq)
    // aliases into dead regions:
    int*   counts = (int*)bufA;   // live only during CSR build (before L0 gather)
    float* z      = (float*)bufB; // live only after L2 bn consumed bufB
    (void)ws_size; (void)n_in;

    // ---- CSR build (once per launch) ----
    hipMemsetAsync(counts, 0, (size_t)N * 4, stream);
    k_hist<<<(E + 255) / 256, 256, 0, stream>>>(edst, counts, E);
    k_scan_fused<<<1, 1024, 0, stream>>>(counts, offs, dinv, N, E);  // counts -> cursor in-place
    k_fill<<<(E + 255) / 256, 256, 0, stream>>>(esrc, edst, dinv, counts, csr, E);
    k_xtohalf<<<(N * DD + 255) / 256, 256, 0, stream>>>(x, m16, N * DD, gstats);

    // rotation: L0: gather(m16 of x)->A, bn: A(+none)->A, m16=h1
    //           L1: gather(m16)->B,      bn: B + res A -> B, m16=h2
    //           L2: gather(m16)->A,      bn: A + res B -> A
    const float* res[3] = {nullptr, bufA, bufB};
    float* ag[3] = {bufA, bufB, bufA};

    for (int l = 0; l < 3; ++l) {
        float* gsum = gstats + l * 128;
        float* gsumsq = gsum + 64;
        k_gather_gemm<<<2048, 256, 0, stream>>>(offs, csr, dinv, (const uint4*)m16,
                                                convW + (size_t)l * DD * DD, convB + l * DD,
                                                ag[l], gsum, gsumsq, N);
        k_bn_ln_gelu<<<2048, 256, 0, stream>>>(ag[l], l ? res[l] : ag[l], gsum, gsumsq,
                                               bn_g + l * DD, bn_b + l * DD,
                                               ln_g + l * DD, ln_b + l * DD,
                                               ag[l], m16, N, l > 0 ? 1 : 0, l < 2 ? 1 : 0);
    }

    k_pool_z<<<G, 64, 0, stream>>>(bufA, batch, z, N);
    k_head<<<G, 128, 0, stream>>>(z, W1, b1, ln1g, ln1b, W2, b2, ln2g, ln2b, W3, b3, out);
}